// Round 7
// baseline (1776.358 us; speedup 1.0000x reference)
//
#include <hip/hip_runtime.h>
#include <math.h>

// Problem constants
#define BDIM 4
#define GDIM 40
#define CDIM 13
#define TDIM 1024
#define FDIM 513                 // T/2 + 1
#define BG   (BDIM*GDIM)         // 160
#define NROW (BG*FDIM)           // 82080 rows of [13] complex
#define QBLK 128                 // Q-rows per block (2 per lane)
#define NCHUNK 5                 // ceil(513/128)
#define NWAVE 4                  // waves per block; f2 axis split 4 ways
#define TILE 32                  // f2 rows staged per LDS tile
#define KVROW 52                 // floats per fused K|V row (26 K + 26 V)
#define MSTRIDE 30               // floats per merge-buffer row (even: aligned v2f)

typedef float v2f __attribute__((ext_vector_type(2)));

__device__ __forceinline__ v2f pkfma(v2f a, v2f b, v2f c) {
    return __builtin_elementwise_fma(a, b, c);
}
__device__ __forceinline__ v2f lo2(float4 v) { v2f r; r.x = v.x; r.y = v.y; return r; }
__device__ __forceinline__ v2f hi2(float4 v) { v2f r; r.x = v.z; r.y = v.w; return r; }

__device__ __forceinline__ unsigned bitrev10(unsigned x) { return __brev(x) >> 22; }

// ---------------- Kernel 1: two-for-one rfft(1024) ----------------
__global__ void fft_fwd2(const float* __restrict__ x, float2* __restrict__ xf) {
    __shared__ float re[1024], im[1024];
    const int s2 = blockIdx.x;                   // pair index, 0..1039
    const float* x1 = x + (size_t)(2 * s2) * TDIM;
    const float* x2 = x1 + TDIM;
    for (int t = threadIdx.x; t < 1024; t += blockDim.x) {
        unsigned r = bitrev10(t);
        re[r] = x1[t];
        im[r] = x2[t];
    }
    __syncthreads();
    for (int s = 0; s < 10; ++s) {
        int half = 1 << s;
        for (int j = threadIdx.x; j < 512; j += blockDim.x) {
            int grp = j >> s;
            int pos = j & (half - 1);
            int i1 = (grp << (s + 1)) + pos;
            int i2 = i1 + half;
            float ang = -(float)M_PI * (float)pos / (float)half;
            float sw, cw; __sincosf(ang, &sw, &cw);
            float xr = re[i2], xi = im[i2];
            float tr = cw * xr - sw * xi;
            float ti = cw * xi + sw * xr;
            float ur = re[i1], ui = im[i1];
            re[i1] = ur + tr; im[i1] = ui + ti;
            re[i2] = ur - tr; im[i2] = ui - ti;
        }
        __syncthreads();
    }
    const int sigA = 2 * s2, sigB = sigA + 1;
    const int bgA = sigA / CDIM, cA = sigA % CDIM;
    const int bgB = sigB / CDIM, cB = sigB % CDIM;
    for (int f = threadIdx.x; f < FDIM; f += blockDim.x) {
        int fr = (1024 - f) & 1023;
        float zr = re[f], zi = im[f];
        float wr = re[fr], wi = im[fr];
        xf[((size_t)bgA * FDIM + f) * CDIM + cA] =
            make_float2(0.5f * (zr + wr), 0.5f * (zi - wi));
        xf[((size_t)bgB * FDIM + f) * CDIM + cB] =
            make_float2(0.5f * (zi + wi), 0.5f * (wr - zr));
    }
}

// ---------------- Kernel 2: Q/K/V; K,V written fused per row ----------------
// q[(bg*F+f)*13+c] complex; kv row = 52 floats: [k0r..k12i | v0r..v12i]
__global__ void qkv_kernel(const float2* __restrict__ xf,
                           const float* __restrict__ wq,
                           const float* __restrict__ wk,
                           const float* __restrict__ wv,
                           float2* __restrict__ q, float* __restrict__ kv) {
    int gid = blockIdx.x * blockDim.x + threadIdx.x;
    if (gid >= NROW * CDIM) return;
    int r = gid / CDIM;
    int i = gid - r * CDIM;
    const float2* xrow = xf + (size_t)r * CDIM;
    float qr = 0, qi = 0, kr = 0, ki = 0, vr = 0, vi = 0;
#pragma unroll
    for (int c = 0; c < CDIM; ++c) {
        float2 xc = xrow[c];
        float a = wq[c * CDIM + i]; qr += xc.x * a; qi += xc.y * a;
        float b = wk[c * CDIM + i]; kr += xc.x * b; ki += xc.y * b;
        float d = wv[c * CDIM + i]; vr += xc.x * d; vi += xc.y * d;
    }
    q[gid] = make_float2(qr, qi);
    float* kvrow = kv + (size_t)r * KVROW;
    kvrow[2 * i]          = kr;
    kvrow[2 * i + 1]      = ki;
    kvrow[26 + 2 * i]     = vr;
    kvrow[26 + 2 * i + 1] = vi;
}

// ---------------- Kernel 3: attention (packed-fp32 math) ----------------
// Block = 4 waves over 128 Q-rows of one (b,g); lane owns f0 and f0+64.
// f2 axis split mod-4 across waves within each 32-row LDS tile of fused K|V
// rows (13 wave-uniform ds_read_b128 per row). Complex dot via v_pk_fma:
// A += qre*(kr,ki), B += qim*(kr,ki); sr=A.x-B.y, si=A.y+B.x. One rescale per
// 4-row batch. Per-wave partials merged sequentially through a 15-KB buffer.
#define QK1(qc, A, B, kp)                                        \
    A = pkfma(__builtin_shufflevector(qc, qc, 0, 0), kp, A);     \
    B = pkfma(__builtin_shufflevector(qc, qc, 1, 1), kp, B);

#define QK13(qc, A, B)                                           \
    QK1(qc[0], A, B, lo2(a0)) QK1(qc[1], A, B, hi2(a0))          \
    QK1(qc[2], A, B, lo2(a1)) QK1(qc[3], A, B, hi2(a1))          \
    QK1(qc[4], A, B, lo2(a2)) QK1(qc[5], A, B, hi2(a2))          \
    QK1(qc[6], A, B, lo2(a3)) QK1(qc[7], A, B, hi2(a3))          \
    QK1(qc[8], A, B, lo2(a4)) QK1(qc[9], A, B, hi2(a4))          \
    QK1(qc[10], A, B, lo2(a5)) QK1(qc[11], A, B, hi2(a5))        \
    QK1(qc[12], A, B, lo2(a6))

#define PV13(acc, pv, vc)                                        \
    acc[0]  = pkfma(pv, vc,      acc[0]);                        \
    acc[1]  = pkfma(pv, lo2(b1), acc[1]);                        \
    acc[2]  = pkfma(pv, hi2(b1), acc[2]);                        \
    acc[3]  = pkfma(pv, lo2(b2), acc[3]);                        \
    acc[4]  = pkfma(pv, hi2(b2), acc[4]);                        \
    acc[5]  = pkfma(pv, lo2(b3), acc[5]);                        \
    acc[6]  = pkfma(pv, hi2(b3), acc[6]);                        \
    acc[7]  = pkfma(pv, lo2(b4), acc[7]);                        \
    acc[8]  = pkfma(pv, hi2(b4), acc[8]);                        \
    acc[9]  = pkfma(pv, lo2(b5), acc[9]);                        \
    acc[10] = pkfma(pv, hi2(b5), acc[10]);                       \
    acc[11] = pkfma(pv, lo2(b6), acc[11]);                       \
    acc[12] = pkfma(pv, hi2(b6), acc[12]);

__global__ __launch_bounds__(256, 3) void attn_kernel(const float2* __restrict__ q,
                                                      const float* __restrict__ kv,
                                                      float2* __restrict__ outspec) {
    __shared__ __align__(16) float4 Kt4[TILE * 13];          // 6656 B (fused K|V tile)
    __shared__ __align__(16) float Mbuf[QBLK * MSTRIDE];     // 15360 B (merge rounds)

    const int bg    = blockIdx.x / NCHUNK;
    const int chunk = blockIdx.x % NCHUNK;
    const int tid   = threadIdx.x;
    const int w     = tid >> 6;
    const int lane  = tid & 63;
    const int f0r   = chunk * QBLK + lane;
    const int f1r   = f0r + 64;
    const bool wr0  = (f0r < FDIM);
    const bool wr1  = (f1r < FDIM);
    const int f0    = wr0 ? f0r : (FDIM - 1);
    const int f1    = wr1 ? f1r : (FDIM - 1);
    const size_t base = (size_t)bg * FDIM;

    v2f qc0[CDIM], qc1[CDIM];
    {
        const float2* qrow0 = q + (base + f0) * CDIM;
        const float2* qrow1 = q + (base + f1) * CDIM;
#pragma unroll
        for (int c = 0; c < CDIM; ++c) {
            float2 t0 = qrow0[c]; qc0[c].x = t0.x; qc0[c].y = t0.y;
            float2 t1 = qrow1[c]; qc1[c].x = t1.x; qc1[c].y = t1.y;
        }
    }

    v2f acc0[CDIM], acc1[CDIM];
#pragma unroll
    for (int c = 0; c < CDIM; ++c) { acc0[c] = (v2f)(0.f); acc1[c] = (v2f)(0.f); }
    float m0 = -INFINITY, l0 = 0.f, m1 = -INFINITY, l1 = 0.f;

    const float* __restrict__ kvbase = kv + base * KVROW;

    for (int t0 = 0; t0 < FDIM; t0 += TILE) {
        const int tl = min(TILE, FDIM - t0);
        __syncthreads();                          // previous tile fully consumed
        {
            const float4* src = (const float4*)(kvbase + (size_t)t0 * KVROW);
            const int n4 = tl * 13;
            for (int i = tid; i < n4; i += 256) Kt4[i] = src[i];
        }
        __syncthreads();

        for (int ib = 0; ib < 2; ++ib) {
            float s0[4], s1[4];
            v2f vcar[4];                          // carried V0 pair from a6 high half
            float tmax0 = -INFINITY, tmax1 = -INFINITY;
#pragma unroll
            for (int rr = 0; rr < 4; ++rr) {
                const int r2 = w + 4 * (ib * 4 + rr);
                if (r2 < tl) {                    // wave-uniform
                    const float4* R = &Kt4[r2 * 13];
                    float4 a0 = R[0], a1 = R[1], a2 = R[2],
                           a3 = R[3], a4 = R[4], a5 = R[5], a6 = R[6];
                    vcar[rr] = hi2(a6);           // (V0r, V0i)
                    v2f A0 = (v2f)(0.f), B0 = (v2f)(0.f);
                    v2f A1 = (v2f)(0.f), B1 = (v2f)(0.f);
                    QK13(qc0, A0, B0)
                    QK13(qc1, A1, B1)
                    float sr0 = A0.x - B0.y, si0 = A0.y + B0.x;
                    float sr1 = A1.x - B1.y, si1 = A1.y + B1.x;
                    float sv0 = __builtin_amdgcn_sqrtf(fmaf(sr0, sr0, si0 * si0));
                    float sv1 = __builtin_amdgcn_sqrtf(fmaf(sr1, sr1, si1 * si1));
                    s0[rr] = sv0; tmax0 = fmaxf(tmax0, sv0);
                    s1[rr] = sv1; tmax1 = fmaxf(tmax1, sv1);
                } else {
                    s0[rr] = -INFINITY; s1[rr] = -INFINITY;
                    vcar[rr] = (v2f)(0.f);
                }
            }
            if (tmax0 > m0) {                     // at most once per batch
                float alpha = __expf(m0 - tmax0); // exp(-inf)=0 covers first batch
                l0 *= alpha;
                v2f av; av.x = alpha; av.y = alpha;
#pragma unroll
                for (int c = 0; c < CDIM; ++c) acc0[c] *= av;
                m0 = tmax0;
            }
            if (tmax1 > m1) {
                float alpha = __expf(m1 - tmax1);
                l1 *= alpha;
                v2f av; av.x = alpha; av.y = alpha;
#pragma unroll
                for (int c = 0; c < CDIM; ++c) acc1[c] *= av;
                m1 = tmax1;
            }
#pragma unroll
            for (int rr = 0; rr < 4; ++rr) {
                const int r2 = w + 4 * (ib * 4 + rr);
                if (r2 < tl) {
                    const float4* R = &Kt4[r2 * 13];
                    float4 b1 = R[7], b2 = R[8], b3 = R[9],
                           b4 = R[10], b5 = R[11], b6 = R[12];
                    float p0 = __expf(s0[rr] - m0);
                    float p1 = __expf(s1[rr] - m1);
                    l0 += p0; l1 += p1;
                    v2f p0v; p0v.x = p0; p0v.y = p0;
                    v2f p1v; p1v.x = p1; p1v.y = p1;
                    PV13(acc0, p0v, vcar[rr])
                    PV13(acc1, p1v, vcar[rr])
                }
            }
        }
    }

    // ---- sequential merge of waves 1..3 into wave 0 via one 128-row buffer ----
#pragma unroll
    for (int p2 = 1; p2 < NWAVE; ++p2) {
        __syncthreads();
        if (w == p2) {
            float* d0 = &Mbuf[lane * MSTRIDE];
            d0[0] = m0; d0[1] = l0;
#pragma unroll
            for (int c = 0; c < CDIM; ++c) *(v2f*)&d0[2 + 2 * c] = acc0[c];
            float* d1 = &Mbuf[(64 + lane) * MSTRIDE];
            d1[0] = m1; d1[1] = l1;
#pragma unroll
            for (int c = 0; c < CDIM; ++c) *(v2f*)&d1[2 + 2 * c] = acc1[c];
        }
        __syncthreads();
        if (w == 0) {
            {
                const float* src = &Mbuf[lane * MSTRIDE];
                float mp = src[0], lp = src[1];
                float M = fmaxf(m0, mp);
                float sa = __expf(m0 - M), sb = __expf(mp - M);
                l0 = l0 * sa + lp * sb;
                v2f sav; sav.x = sa; sav.y = sa;
                v2f sbv; sbv.x = sb; sbv.y = sb;
#pragma unroll
                for (int c = 0; c < CDIM; ++c)
                    acc0[c] = pkfma(sbv, *(const v2f*)&src[2 + 2 * c], acc0[c] * sav);
                m0 = M;
            }
            {
                const float* src = &Mbuf[(64 + lane) * MSTRIDE];
                float mp = src[0], lp = src[1];
                float M = fmaxf(m1, mp);
                float sa = __expf(m1 - M), sb = __expf(mp - M);
                l1 = l1 * sa + lp * sb;
                v2f sav; sav.x = sa; sav.y = sa;
                v2f sbv; sbv.x = sb; sbv.y = sb;
#pragma unroll
                for (int c = 0; c < CDIM; ++c)
                    acc1[c] = pkfma(sbv, *(const v2f*)&src[2 + 2 * c], acc1[c] * sav);
                m1 = M;
            }
        }
    }
    if (w == 0) {
        if (wr0) {
            float inv = 1.f / l0;
#pragma unroll
            for (int c = 0; c < CDIM; ++c)
                outspec[((size_t)(bg * CDIM + c)) * FDIM + f0] =
                    make_float2(acc0[c].x * inv, acc0[c].y * inv);
        }
        if (wr1) {
            float inv = 1.f / l1;
#pragma unroll
            for (int c = 0; c < CDIM; ++c)
                outspec[((size_t)(bg * CDIM + c)) * FDIM + f1] =
                    make_float2(acc1[c].x * inv, acc1[c].y * inv);
        }
    }
}

// ---------------- Kernel 4: two-for-one irfft(1024) ----------------
__global__ void fft_inv2(const float2* __restrict__ spec, float* __restrict__ out) {
    __shared__ float re[1024], im[1024];
    const int s2 = blockIdx.x;                   // pair 0..1039
    const float2* Y1 = spec + (size_t)(2 * s2) * FDIM;
    const float2* Y2 = Y1 + FDIM;
    for (int t = threadIdx.x; t < 1024; t += blockDim.x) {
        float a, b, c, d;
        if (t <= 512) {
            float2 y1 = Y1[t], y2 = Y2[t];
            bool edge = (t == 0) | (t == 512);
            a = y1.x; b = edge ? 0.f : y1.y;
            c = y2.x; d = edge ? 0.f : y2.y;
        } else {
            float2 y1 = Y1[1024 - t], y2 = Y2[1024 - t];
            a = y1.x; b = -y1.y;
            c = y2.x; d = -y2.y;
        }
        unsigned r = bitrev10(t);
        re[r] = a - d;                            // Re(Y1h + i*Y2h)
        im[r] = b + c;                            // Im(Y1h + i*Y2h)
    }
    __syncthreads();
    for (int s = 0; s < 10; ++s) {
        int half = 1 << s;
        for (int j = threadIdx.x; j < 512; j += blockDim.x) {
            int grp = j >> s;
            int pos = j & (half - 1);
            int i1 = (grp << (s + 1)) + pos;
            int i2 = i1 + half;
            float ang = (float)M_PI * (float)pos / (float)half;   // +sign = inverse
            float sw, cw; __sincosf(ang, &sw, &cw);
            float xr = re[i2], xi = im[i2];
            float tr = cw * xr - sw * xi;
            float ti = cw * xi + sw * xr;
            float ur = re[i1], ui = im[i1];
            re[i1] = ur + tr; im[i1] = ui + ti;
            re[i2] = ur - tr; im[i2] = ui - ti;
        }
        __syncthreads();
    }
    const float scale = 1.0f / 1024.0f;
    float* o1 = out + (size_t)(2 * s2) * TDIM;
    for (int t = threadIdx.x; t < 1024; t += blockDim.x) {
        o1[t]        = re[t] * scale;
        o1[TDIM + t] = im[t] * scale;
    }
}

extern "C" void kernel_launch(void* const* d_in, const int* in_sizes, int n_in,
                              void* d_out, int out_size, void* d_ws, size_t ws_size,
                              hipStream_t stream) {
    const float* x  = (const float*)d_in[0];
    const float* wq = (const float*)d_in[1];
    const float* wk = (const float*)d_in[2];
    const float* wv = (const float*)d_in[3];
    float* out = (float*)d_out;

    const size_t n = (size_t)NROW * CDIM;        // 1,067,040 complex
    float2* xf = (float2*)d_ws;                  // x_fft, later reused as out-spectrum
    float2* q  = xf + n;                         // n float2
    float*  kv = (float*)(q + n);                // NROW * 52 floats (fused K|V)

    fft_fwd2<<<BG * CDIM / 2, 256, 0, stream>>>(x, xf);
    qkv_kernel<<<(NROW * CDIM + 255) / 256, 256, 0, stream>>>(xf, wq, wk, wv, q, kv);
    attn_kernel<<<BG * NCHUNK, 256, 0, stream>>>(q, kv, xf /* outspec, aliases xf */);
    fft_inv2<<<BG * CDIM / 2, 256, 0, stream>>>(xf, out);
}

// Round 8
// 294.943 us; speedup vs baseline: 6.0227x; 6.0227x over previous
//
#include <hip/hip_runtime.h>
#include <math.h>

// Problem constants
#define BDIM 4
#define GDIM 40
#define CDIM 13
#define TDIM 1024
#define FDIM 513                 // T/2 + 1
#define BG   (BDIM*GDIM)         // 160
#define NROW (BG*FDIM)           // 82080 rows of [13] complex
#define QBLK 128                 // Q-rows per block (2 per lane)
#define NCHUNK 5                 // ceil(513/128)
#define NWAVE 4                  // waves per block; f2 axis split 4 ways
#define TILE 32                  // f2 rows staged per LDS tile
#define KVROW 52                 // floats per fused K|V row (26 K + 26 V)
#define MSTRIDE 29               // floats per merge-buffer row

__device__ __forceinline__ unsigned bitrev10(unsigned x) { return __brev(x) >> 22; }

// ---------------- Kernel 1: two-for-one rfft(1024) ----------------
__global__ void fft_fwd2(const float* __restrict__ x, float2* __restrict__ xf) {
    __shared__ float re[1024], im[1024];
    const int s2 = blockIdx.x;                   // pair index, 0..1039
    const float* x1 = x + (size_t)(2 * s2) * TDIM;
    const float* x2 = x1 + TDIM;
    for (int t = threadIdx.x; t < 1024; t += blockDim.x) {
        unsigned r = bitrev10(t);
        re[r] = x1[t];
        im[r] = x2[t];
    }
    __syncthreads();
    for (int s = 0; s < 10; ++s) {
        int half = 1 << s;
        for (int j = threadIdx.x; j < 512; j += blockDim.x) {
            int grp = j >> s;
            int pos = j & (half - 1);
            int i1 = (grp << (s + 1)) + pos;
            int i2 = i1 + half;
            float ang = -(float)M_PI * (float)pos / (float)half;
            float sw, cw; __sincosf(ang, &sw, &cw);
            float xr = re[i2], xi = im[i2];
            float tr = cw * xr - sw * xi;
            float ti = cw * xi + sw * xr;
            float ur = re[i1], ui = im[i1];
            re[i1] = ur + tr; im[i1] = ui + ti;
            re[i2] = ur - tr; im[i2] = ui - ti;
        }
        __syncthreads();
    }
    const int sigA = 2 * s2, sigB = sigA + 1;
    const int bgA = sigA / CDIM, cA = sigA % CDIM;
    const int bgB = sigB / CDIM, cB = sigB % CDIM;
    for (int f = threadIdx.x; f < FDIM; f += blockDim.x) {
        int fr = (1024 - f) & 1023;
        float zr = re[f], zi = im[f];
        float wr = re[fr], wi = im[fr];
        xf[((size_t)bgA * FDIM + f) * CDIM + cA] =
            make_float2(0.5f * (zr + wr), 0.5f * (zi - wi));
        xf[((size_t)bgB * FDIM + f) * CDIM + cB] =
            make_float2(0.5f * (zi + wi), 0.5f * (wr - zr));
    }
}

// ---------------- Kernel 2: Q/K/V; K,V written fused per row ----------------
// q[(bg*F+f)*13+c] complex; kv row = 52 floats: [k0r..k12i | v0r..v12i]
__global__ void qkv_kernel(const float2* __restrict__ xf,
                           const float* __restrict__ wq,
                           const float* __restrict__ wk,
                           const float* __restrict__ wv,
                           float2* __restrict__ q, float* __restrict__ kv) {
    int gid = blockIdx.x * blockDim.x + threadIdx.x;
    if (gid >= NROW * CDIM) return;
    int r = gid / CDIM;
    int i = gid - r * CDIM;
    const float2* xrow = xf + (size_t)r * CDIM;
    float qr = 0, qi = 0, kr = 0, ki = 0, vr = 0, vi = 0;
#pragma unroll
    for (int c = 0; c < CDIM; ++c) {
        float2 xc = xrow[c];
        float a = wq[c * CDIM + i]; qr += xc.x * a; qi += xc.y * a;
        float b = wk[c * CDIM + i]; kr += xc.x * b; ki += xc.y * b;
        float d = wv[c * CDIM + i]; vr += xc.x * d; vi += xc.y * d;
    }
    q[gid] = make_float2(qr, qi);
    float* kvrow = kv + (size_t)r * KVROW;
    kvrow[2 * i]          = kr;
    kvrow[2 * i + 1]      = ki;
    kvrow[26 + 2 * i]     = vr;
    kvrow[26 + 2 * i + 1] = vi;
}

// ---------------- Kernel 3: attention ----------------
// Block = 4 waves over 128 Q-rows of one (b,g); lane owns f0=chunk*128+lane and
// f1=f0+64 (two online-softmax states, SCALAR floats — vector-typed register
// arrays spill to scratch on this compiler, R7). f2 axis split mod-4 across
// waves within each 32-row LDS tile of fused K|V rows (13 wave-uniform
// ds_read_b128 per row, broadcast, conflict-free). One rescale per 4-row
// batch. launch_bounds(256,2): 256-VGPR cap so the ~165 live floats fit
// without AGPR shuttling (R6: cap 170 -> compiler spilled at 84).
// Per-wave partials merged sequentially through one 128-row LDS buffer.
#define CMACQ(qre, qim, c0, kk)                                  \
    sr = fmaf(qre[c0], kk.x, sr); sr = fmaf(-qim[c0], kk.y, sr);   \
    si = fmaf(qre[c0], kk.y, si); si = fmaf(qim[c0], kk.x, si);    \
    sr = fmaf(qre[(c0)+1], kk.z, sr); sr = fmaf(-qim[(c0)+1], kk.w, sr); \
    si = fmaf(qre[(c0)+1], kk.w, si); si = fmaf(qim[(c0)+1], kk.z, si);

#define PVQ(ar, ai, p, c0, vv)                                   \
    ar[c0] = fmaf(p, vv.x, ar[c0]); ai[c0] = fmaf(p, vv.y, ai[c0]); \
    ar[(c0)+1] = fmaf(p, vv.z, ar[(c0)+1]); ai[(c0)+1] = fmaf(p, vv.w, ai[(c0)+1]);

__global__ __launch_bounds__(256, 2) void attn_kernel(const float2* __restrict__ q,
                                                      const float* __restrict__ kv,
                                                      float2* __restrict__ outspec) {
    __shared__ __align__(16) float4 Kt4[TILE * 13];          // 6656 B (fused K|V tile)
    __shared__ float Mbuf[QBLK * MSTRIDE];                   // 14848 B (merge rounds)

    const int bg    = blockIdx.x / NCHUNK;
    const int chunk = blockIdx.x % NCHUNK;
    const int tid   = threadIdx.x;
    const int w     = tid >> 6;
    const int lane  = tid & 63;
    const int f0r   = chunk * QBLK + lane;
    const int f1r   = f0r + 64;
    const bool wr0  = (f0r < FDIM);
    const bool wr1  = (f1r < FDIM);
    const int f0    = wr0 ? f0r : (FDIM - 1);
    const int f1    = wr1 ? f1r : (FDIM - 1);
    const size_t base = (size_t)bg * FDIM;

    float qre0[CDIM], qim0[CDIM], qre1[CDIM], qim1[CDIM];
    {
        const float2* qrow0 = q + (base + f0) * CDIM;
        const float2* qrow1 = q + (base + f1) * CDIM;
#pragma unroll
        for (int c = 0; c < CDIM; ++c) {
            float2 t0 = qrow0[c]; qre0[c] = t0.x; qim0[c] = t0.y;
            float2 t1 = qrow1[c]; qre1[c] = t1.x; qim1[c] = t1.y;
        }
    }

    float ar0[CDIM], ai0[CDIM], ar1[CDIM], ai1[CDIM];
#pragma unroll
    for (int c = 0; c < CDIM; ++c) { ar0[c] = ai0[c] = ar1[c] = ai1[c] = 0.f; }
    float m0 = -INFINITY, l0 = 0.f, m1 = -INFINITY, l1 = 0.f;

    const float* __restrict__ kvbase = kv + base * KVROW;

    for (int t0 = 0; t0 < FDIM; t0 += TILE) {
        const int tl = min(TILE, FDIM - t0);
        __syncthreads();                          // previous tile fully consumed
        {
            const float4* src = (const float4*)(kvbase + (size_t)t0 * KVROW);
            const int n4 = tl * 13;
            for (int i = tid; i < n4; i += 256) Kt4[i] = src[i];
        }
        __syncthreads();

        for (int ib = 0; ib < 2; ++ib) {
            float s0[4], s1[4];
            float2 vcar[4];                       // carried V0 from the shared b128
            float tmax0 = -INFINITY, tmax1 = -INFINITY;
#pragma unroll
            for (int rr = 0; rr < 4; ++rr) {
                const int r2 = w + 4 * (ib * 4 + rr);
                if (r2 < tl) {                    // wave-uniform
                    const float4* R = &Kt4[r2 * 13];
                    float4 a0 = R[0], a1 = R[1], a2 = R[2],
                           a3 = R[3], a4 = R[4], a5 = R[5], a6 = R[6];
                    vcar[rr] = make_float2(a6.z, a6.w);       // V0r, V0i
                    float sr, si;
                    sr = 0.f; si = 0.f;
                    CMACQ(qre0, qim0, 0, a0) CMACQ(qre0, qim0, 2, a1)
                    CMACQ(qre0, qim0, 4, a2) CMACQ(qre0, qim0, 6, a3)
                    CMACQ(qre0, qim0, 8, a4) CMACQ(qre0, qim0, 10, a5)
                    sr = fmaf(qre0[12], a6.x, sr); sr = fmaf(-qim0[12], a6.y, sr);
                    si = fmaf(qre0[12], a6.y, si); si = fmaf(qim0[12], a6.x, si);
                    float sv0 = __builtin_amdgcn_sqrtf(fmaf(sr, sr, si * si));
                    s0[rr] = sv0; tmax0 = fmaxf(tmax0, sv0);
                    sr = 0.f; si = 0.f;
                    CMACQ(qre1, qim1, 0, a0) CMACQ(qre1, qim1, 2, a1)
                    CMACQ(qre1, qim1, 4, a2) CMACQ(qre1, qim1, 6, a3)
                    CMACQ(qre1, qim1, 8, a4) CMACQ(qre1, qim1, 10, a5)
                    sr = fmaf(qre1[12], a6.x, sr); sr = fmaf(-qim1[12], a6.y, sr);
                    si = fmaf(qre1[12], a6.y, si); si = fmaf(qim1[12], a6.x, si);
                    float sv1 = __builtin_amdgcn_sqrtf(fmaf(sr, sr, si * si));
                    s1[rr] = sv1; tmax1 = fmaxf(tmax1, sv1);
                } else {
                    s0[rr] = -INFINITY; s1[rr] = -INFINITY;
                    vcar[rr] = make_float2(0.f, 0.f);
                }
            }
            if (tmax0 > m0) {                     // at most once per batch
                float alpha = __expf(m0 - tmax0); // exp(-inf)=0 covers first batch
                l0 *= alpha;
#pragma unroll
                for (int c = 0; c < CDIM; ++c) { ar0[c] *= alpha; ai0[c] *= alpha; }
                m0 = tmax0;
            }
            if (tmax1 > m1) {
                float alpha = __expf(m1 - tmax1);
                l1 *= alpha;
#pragma unroll
                for (int c = 0; c < CDIM; ++c) { ar1[c] *= alpha; ai1[c] *= alpha; }
                m1 = tmax1;
            }
#pragma unroll
            for (int rr = 0; rr < 4; ++rr) {
                const int r2 = w + 4 * (ib * 4 + rr);
                if (r2 < tl) {
                    const float4* R = &Kt4[r2 * 13];
                    float4 b1 = R[7], b2 = R[8], b3 = R[9],
                           b4 = R[10], b5 = R[11], b6 = R[12];
                    float p0 = __expf(s0[rr] - m0);
                    float p1 = __expf(s1[rr] - m1);
                    l0 += p0; l1 += p1;
                    float2 v0 = vcar[rr];
                    ar0[0] = fmaf(p0, v0.x, ar0[0]); ai0[0] = fmaf(p0, v0.y, ai0[0]);
                    PVQ(ar0, ai0, p0, 1, b1) PVQ(ar0, ai0, p0, 3, b2)
                    PVQ(ar0, ai0, p0, 5, b3) PVQ(ar0, ai0, p0, 7, b4)
                    PVQ(ar0, ai0, p0, 9, b5) PVQ(ar0, ai0, p0, 11, b6)
                    ar1[0] = fmaf(p1, v0.x, ar1[0]); ai1[0] = fmaf(p1, v0.y, ai1[0]);
                    PVQ(ar1, ai1, p1, 1, b1) PVQ(ar1, ai1, p1, 3, b2)
                    PVQ(ar1, ai1, p1, 5, b3) PVQ(ar1, ai1, p1, 7, b4)
                    PVQ(ar1, ai1, p1, 9, b5) PVQ(ar1, ai1, p1, 11, b6)
                }
            }
        }
    }

    // ---- sequential merge of waves 1..3 into wave 0 via one 128-row buffer ----
#pragma unroll
    for (int p2 = 1; p2 < NWAVE; ++p2) {
        __syncthreads();
        if (w == p2) {
            float* d0 = &Mbuf[lane * MSTRIDE];
            d0[0] = m0; d0[1] = l0;
#pragma unroll
            for (int c = 0; c < CDIM; ++c) { d0[2 + 2 * c] = ar0[c]; d0[3 + 2 * c] = ai0[c]; }
            float* d1 = &Mbuf[(64 + lane) * MSTRIDE];
            d1[0] = m1; d1[1] = l1;
#pragma unroll
            for (int c = 0; c < CDIM; ++c) { d1[2 + 2 * c] = ar1[c]; d1[3 + 2 * c] = ai1[c]; }
        }
        __syncthreads();
        if (w == 0) {
            {
                const float* src = &Mbuf[lane * MSTRIDE];
                float mp = src[0], lp = src[1];
                float M = fmaxf(m0, mp);
                float sa = __expf(m0 - M), sb = __expf(mp - M);
                l0 = l0 * sa + lp * sb;
#pragma unroll
                for (int c = 0; c < CDIM; ++c) {
                    ar0[c] = ar0[c] * sa + src[2 + 2 * c] * sb;
                    ai0[c] = ai0[c] * sa + src[3 + 2 * c] * sb;
                }
                m0 = M;
            }
            {
                const float* src = &Mbuf[(64 + lane) * MSTRIDE];
                float mp = src[0], lp = src[1];
                float M = fmaxf(m1, mp);
                float sa = __expf(m1 - M), sb = __expf(mp - M);
                l1 = l1 * sa + lp * sb;
#pragma unroll
                for (int c = 0; c < CDIM; ++c) {
                    ar1[c] = ar1[c] * sa + src[2 + 2 * c] * sb;
                    ai1[c] = ai1[c] * sa + src[3 + 2 * c] * sb;
                }
                m1 = M;
            }
        }
    }
    if (w == 0) {
        if (wr0) {
            float inv = 1.f / l0;
#pragma unroll
            for (int c = 0; c < CDIM; ++c)
                outspec[((size_t)(bg * CDIM + c)) * FDIM + f0] =
                    make_float2(ar0[c] * inv, ai0[c] * inv);
        }
        if (wr1) {
            float inv = 1.f / l1;
#pragma unroll
            for (int c = 0; c < CDIM; ++c)
                outspec[((size_t)(bg * CDIM + c)) * FDIM + f1] =
                    make_float2(ar1[c] * inv, ai1[c] * inv);
        }
    }
}

// ---------------- Kernel 4: two-for-one irfft(1024) ----------------
__global__ void fft_inv2(const float2* __restrict__ spec, float* __restrict__ out) {
    __shared__ float re[1024], im[1024];
    const int s2 = blockIdx.x;                   // pair 0..1039
    const float2* Y1 = spec + (size_t)(2 * s2) * FDIM;
    const float2* Y2 = Y1 + FDIM;
    for (int t = threadIdx.x; t < 1024; t += blockDim.x) {
        float a, b, c, d;
        if (t <= 512) {
            float2 y1 = Y1[t], y2 = Y2[t];
            bool edge = (t == 0) | (t == 512);
            a = y1.x; b = edge ? 0.f : y1.y;
            c = y2.x; d = edge ? 0.f : y2.y;
        } else {
            float2 y1 = Y1[1024 - t], y2 = Y2[1024 - t];
            a = y1.x; b = -y1.y;
            c = y2.x; d = -y2.y;
        }
        unsigned r = bitrev10(t);
        re[r] = a - d;                            // Re(Y1h + i*Y2h)
        im[r] = b + c;                            // Im(Y1h + i*Y2h)
    }
    __syncthreads();
    for (int s = 0; s < 10; ++s) {
        int half = 1 << s;
        for (int j = threadIdx.x; j < 512; j += blockDim.x) {
            int grp = j >> s;
            int pos = j & (half - 1);
            int i1 = (grp << (s + 1)) + pos;
            int i2 = i1 + half;
            float ang = (float)M_PI * (float)pos / (float)half;   // +sign = inverse
            float sw, cw; __sincosf(ang, &sw, &cw);
            float xr = re[i2], xi = im[i2];
            float tr = cw * xr - sw * xi;
            float ti = cw * xi + sw * xr;
            float ur = re[i1], ui = im[i1];
            re[i1] = ur + tr; im[i1] = ui + ti;
            re[i2] = ur - tr; im[i2] = ui - ti;
        }
        __syncthreads();
    }
    const float scale = 1.0f / 1024.0f;
    float* o1 = out + (size_t)(2 * s2) * TDIM;
    for (int t = threadIdx.x; t < 1024; t += blockDim.x) {
        o1[t]        = re[t] * scale;
        o1[TDIM + t] = im[t] * scale;
    }
}

extern "C" void kernel_launch(void* const* d_in, const int* in_sizes, int n_in,
                              void* d_out, int out_size, void* d_ws, size_t ws_size,
                              hipStream_t stream) {
    const float* x  = (const float*)d_in[0];
    const float* wq = (const float*)d_in[1];
    const float* wk = (const float*)d_in[2];
    const float* wv = (const float*)d_in[3];
    float* out = (float*)d_out;

    const size_t n = (size_t)NROW * CDIM;        // 1,067,040 complex
    float2* xf = (float2*)d_ws;                  // x_fft, later reused as out-spectrum
    float2* q  = xf + n;                         // n float2
    float*  kv = (float*)(q + n);                // NROW * 52 floats (fused K|V)

    fft_fwd2<<<BG * CDIM / 2, 256, 0, stream>>>(x, xf);
    qkv_kernel<<<(NROW * CDIM + 255) / 256, 256, 0, stream>>>(xf, wq, wk, wv, q, kv);
    attn_kernel<<<BG * NCHUNK, 256, 0, stream>>>(q, kv, xf /* outspec, aliases xf */);
    fft_inv2<<<BG * CDIM / 2, 256, 0, stream>>>(xf, out);
}